// Round 1
// baseline (218.039 us; speedup 1.0000x reference)
//
#include <hip/hip_runtime.h>

// Agent-aware MHA, MI355X (gfx950).
// L=1024, N=8, E=512, H=8, D=64. B-heads = 64. All GEMM/attn in bf16 MFMA.
// Tolerance is ~2% of max|ref| (1.1e-3) -> bf16 pipeline is within budget.

typedef float f32x4 __attribute__((ext_vector_type(4)));
typedef short s16x8 __attribute__((ext_vector_type(8)));
typedef unsigned short u16;
typedef u16 u16x4 __attribute__((ext_vector_type(4)));
typedef unsigned int u32x2 __attribute__((ext_vector_type(2)));

#define MFMA16(a, b, c) __builtin_amdgcn_mfma_f32_16x16x32_bf16((a), (b), (c), 0, 0, 0)

__device__ __forceinline__ u16 f2bf(float f) {
  __bf16 h = (__bf16)f;  // RNE
  return __builtin_bit_cast(u16, h);
}
__device__ __forceinline__ unsigned int pack2(float a, float b) {
  return (unsigned int)f2bf(a) | ((unsigned int)f2bf(b) << 16);
}
__device__ __forceinline__ void gload_lds16(const u16* g, u16* l) {
  __builtin_amdgcn_global_load_lds(
      (const __attribute__((address_space(1))) void*)g,
      (__attribute__((address_space(3))) void*)l, 16, 0, 0);
}

// ---------------------------------------------------------------------------
// Kernel 0: fp32 -> bf16 convert with k-chunk XOR swizzle (rows of length 512).
// Stored layout: out[r][k ^ (((r>>1)&3)<<3)] = in[r][k]. Keeps GEMM LDS reads
// ~2-way bank conflicted while global_load_lds stays linear.
// ---------------------------------------------------------------------------
__global__ __launch_bounds__(256) void cvt_swz(const float* __restrict__ in,
                                               u16* __restrict__ out, int n4) {
  int i = blockIdx.x * 256 + threadIdx.x;
  if (i >= n4) return;
  f32x4 v = *(const f32x4*)(in + (size_t)i * 4);
  int e = i << 2;
  int r = e >> 9;
  int k = e & 511;
  int ks = k ^ (((r >> 1) & 3) << 3);
  u16x4 o;
  o[0] = f2bf(v[0]); o[1] = f2bf(v[1]); o[2] = f2bf(v[2]); o[3] = f2bf(v[3]);
  *(u16x4*)(out + ((size_t)r << 9) + ks) = o;
}

// ---------------------------------------------------------------------------
// Kernel 1: in_proj GEMM  P = X(8192x512) * W^T(512x2560) + bias
// m97-style: 128x128 tile, BK=32, 4 waves (2x2), 4x4 frags/wave.
// Epilogue scatters into per-head Q/K/Vt/Qs/Ks bf16 tensors:
//   Q,Qs : [bh][l][d]               (scaled by 0.125*log2e)
//   K,Ks : [bh][s][d ^ ((s&7)<<3)]  (d-swizzled for conflict-free ds_read)
//   Vt   : [bh][d][s ^ ((d&7)<<3)]  (transposed + s-swizzled)
// ---------------------------------------------------------------------------
__global__ __launch_bounds__(256) void gemm_inproj(
    const u16* __restrict__ X, const u16* __restrict__ W,
    const float* __restrict__ bias,
    u16* __restrict__ Qg, u16* __restrict__ Kg, u16* __restrict__ Vtg,
    u16* __restrict__ Qsg, u16* __restrict__ Ksg) {
  __shared__ __attribute__((aligned(16))) u16 At[128 * 32];
  __shared__ __attribute__((aligned(16))) u16 Bt[128 * 32];
  const int tid = threadIdx.x;
  const int lane = tid & 63, w = tid >> 6;
  const int lr = lane & 15, lq = lane >> 4;
  const int wr = w >> 1, wc = w & 1;
  const int tm = blockIdx.x * 128, tn = blockIdx.y * 128;

  f32x4 acc[4][4] = {};

  for (int k0 = 0; k0 < 512; k0 += 32) {
    if (k0) __syncthreads();
#pragma unroll
    for (int j = 0; j < 2; ++j) {
      const int c = (w * 2 + j) * 64 + lane;  // 16B chunk index, 512 per tile
      const int row = c >> 2;
      const int col = (c & 3) * 8;
      gload_lds16(X + (size_t)(tm + row) * 512 + k0 + col, At + (w * 2 + j) * 512);
      gload_lds16(W + (size_t)(tn + row) * 512 + k0 + col, Bt + (w * 2 + j) * 512);
    }
    __syncthreads();
    s16x8 af[4], bf[4];
#pragma unroll
    for (int mi = 0; mi < 4; ++mi) {
      const int row = wr * 64 + mi * 16 + lr;
      const int col = (lq * 8) ^ ((((tm + row) >> 1) & 3) << 3);
      af[mi] = *(const s16x8*)(At + row * 32 + col);
    }
#pragma unroll
    for (int ni = 0; ni < 4; ++ni) {
      const int row = wc * 64 + ni * 16 + lr;
      const int col = (lq * 8) ^ ((((tn + row) >> 1) & 3) << 3);
      bf[ni] = *(const s16x8*)(Bt + row * 32 + col);
    }
#pragma unroll
    for (int mi = 0; mi < 4; ++mi)
#pragma unroll
      for (int ni = 0; ni < 4; ++ni)
        acc[mi][ni] = MFMA16(af[mi], bf[ni], acc[mi][ni]);
  }

  // Epilogue. chunk (which of q,k,v,q_same,k_same) is block-uniform: 512/128=4 tiles per chunk.
  const int chunk = tn >> 9;
  const float qscale = 0.125f * 1.4426950408889634f;  // scaling * log2(e): exp -> exp2
#pragma unroll
  for (int ni = 0; ni < 4; ++ni) {
    const int gc = tn + wc * 64 + ni * 16 + lr;
    const float bv = bias[gc];
    const int e = gc & 511;
    const int hh = e >> 6, dd = e & 63;
#pragma unroll
    for (int mi = 0; mi < 4; ++mi) {
#pragma unroll
      for (int r = 0; r < 4; ++r) {
        const int gr = tm + wr * 64 + mi * 16 + lq * 4 + r;  // C/D: row=(lane>>4)*4+reg
        const int l = gr >> 3, nn = gr & 7;
        const size_t base = (size_t)(nn * 8 + hh) << 16;  // bh * L * D
        float v = acc[mi][ni][r] + bv;
        if (chunk == 0) {
          Qg[base + l * 64 + dd] = f2bf(v * qscale);
        } else if (chunk == 3) {
          Qsg[base + l * 64 + dd] = f2bf(v * qscale);
        } else if (chunk == 1) {
          Kg[base + l * 64 + (dd ^ ((l & 7) << 3))] = f2bf(v);
        } else if (chunk == 4) {
          Ksg[base + l * 64 + (dd ^ ((l & 7) << 3))] = f2bf(v);
        } else {  // chunk == 2: V stored transposed [bh][d][s], s-swizzled
          Vtg[base + (size_t)dd * 1024 + (l ^ ((dd & 7) << 3))] = f2bf(v);
        }
      }
    }
  }
}

// ---------------------------------------------------------------------------
// Kernel 2: fused dual attention, one block = (128 q-rows, one b-head).
// Swapped QK^T: S^T = mfma(K, Q) so per-lane mask loads are contiguous float4
// and row-softmax reduces with 2 shfl_xor. Online softmax in exp2 domain.
// PV computed as O^T = V^T * P^T (Vt already transposed in global).
// ---------------------------------------------------------------------------
__global__ __launch_bounds__(256) void attn_kernel(
    const u16* __restrict__ Qg, const u16* __restrict__ Kg,
    const u16* __restrict__ Vtg, const u16* __restrict__ Qsg,
    const u16* __restrict__ Ksg, const float* __restrict__ mask,
    u16* __restrict__ Og) {
  __shared__ __attribute__((aligned(16))) u16 Kt[64 * 64];
  __shared__ __attribute__((aligned(16))) u16 Kst[64 * 64];
  __shared__ __attribute__((aligned(16))) u16 Vt[64 * 64];
  __shared__ __attribute__((aligned(16))) u16 Pl[4][32 * 72];  // wave-private, padded

  const int tid = threadIdx.x;
  const int lane = tid & 63, w = tid >> 6;
  const int lr = lane & 15, lq = lane >> 4;
  const int bh = blockIdx.y;
  const int q0 = blockIdx.x * 128;
  const size_t bbase = (size_t)bh << 16;
  const int nn = bh >> 3, hh = bh & 7;

  // Q fragments (B-operand layout: n = l = lane&15, k = d contiguous). Held all loop.
  s16x8 qf[2][2], qsf[2][2];
#pragma unroll
  for (int nl = 0; nl < 2; ++nl) {
    const int l = q0 + w * 32 + nl * 16 + lr;
#pragma unroll
    for (int ks = 0; ks < 2; ++ks) {
      qf[nl][ks] = *(const s16x8*)(Qg + bbase + (size_t)l * 64 + ks * 32 + lq * 8);
      qsf[nl][ks] = *(const s16x8*)(Qsg + bbase + (size_t)l * 64 + ks * 32 + lq * 8);
    }
  }

  f32x4 oacc[4][2] = {};            // [dmi][nl], O^T fragments
  float m_run[2] = {-1e30f, -1e30f};
  float l_run[2] = {0.f, 0.f};

  for (int t = 0; t < 16; ++t) {
    const int s0 = t * 64;
    if (t) __syncthreads();  // prior-iter LDS reads done before restage
#pragma unroll
    for (int j = 0; j < 2; ++j) {
      const int cb = (w * 2 + j) * 64;
      const int c = cb + lane;
      const int row = c >> 3, col = (c & 7) * 8;
      gload_lds16(Kg + bbase + (size_t)(s0 + row) * 64 + col, Kt + cb * 8);
      gload_lds16(Ksg + bbase + (size_t)(s0 + row) * 64 + col, Kst + cb * 8);
      gload_lds16(Vtg + bbase + (size_t)row * 1024 + s0 + col, Vt + cb * 8);
    }
    __syncthreads();

    // S^T = K * Q^T (A = K rows=s, B = Q^T cols=l)
    f32x4 sd[4][2] = {}, ss[4][2] = {};
#pragma unroll
    for (int smi = 0; smi < 4; ++smi) {
      const int srow = smi * 16 + lr;
#pragma unroll
      for (int ks = 0; ks < 2; ++ks) {
        const int off = srow * 64 + ((ks * 32 + lq * 8) ^ ((srow & 7) << 3));
        const s16x8 kf = *(const s16x8*)(Kt + off);
        const s16x8 ksf = *(const s16x8*)(Kst + off);
#pragma unroll
        for (int nl = 0; nl < 2; ++nl) {
          sd[smi][nl] = MFMA16(kf, qf[nl][ks], sd[smi][nl]);
          ss[smi][nl] = MFMA16(ksf, qsf[nl][ks], ss[smi][nl]);
        }
      }
    }

    // combine with mask: logit = sd + m*(ss-sd)  (already in exp2 domain)
    float mt[2] = {-1e30f, -1e30f};
#pragma unroll
    for (int smi = 0; smi < 4; ++smi) {
#pragma unroll
      for (int nl = 0; nl < 2; ++nl) {
        const int l = q0 + w * 32 + nl * 16 + lr;
        const f32x4 mk =
            *(const f32x4*)(mask + (size_t)l * 1024 + s0 + smi * 16 + lq * 4);
#pragma unroll
        for (int r = 0; r < 4; ++r) {
          const float v = sd[smi][nl][r] + mk[r] * (ss[smi][nl][r] - sd[smi][nl][r]);
          sd[smi][nl][r] = v;
          mt[nl] = fmaxf(mt[nl], v);
        }
      }
    }
    // row max across the 4 lane-quads holding the same l
#pragma unroll
    for (int nl = 0; nl < 2; ++nl) {
      float m2 = fmaxf(mt[nl], __shfl_xor(mt[nl], 16));
      m2 = fmaxf(m2, __shfl_xor(m2, 32));
      mt[nl] = m2;
    }
    float mnew[2], scale[2];
#pragma unroll
    for (int nl = 0; nl < 2; ++nl) {
      mnew[nl] = fmaxf(m_run[nl], mt[nl]);
      scale[nl] = exp2f(m_run[nl] - mnew[nl]);
      m_run[nl] = mnew[nl];
    }
    float ts[2] = {0.f, 0.f};
#pragma unroll
    for (int smi = 0; smi < 4; ++smi)
#pragma unroll
      for (int nl = 0; nl < 2; ++nl)
#pragma unroll
        for (int r = 0; r < 4; ++r) {
          const float p = exp2f(sd[smi][nl][r] - mnew[nl]);
          sd[smi][nl][r] = p;
          ts[nl] += p;
        }
    // P -> wave-private LDS in [l][s] layout (B-operand for PV)
#pragma unroll
    for (int smi = 0; smi < 4; ++smi)
#pragma unroll
      for (int nl = 0; nl < 2; ++nl) {
        u32x2 pw;
        pw[0] = pack2(sd[smi][nl][0], sd[smi][nl][1]);
        pw[1] = pack2(sd[smi][nl][2], sd[smi][nl][3]);
        *(u32x2*)(&Pl[w][(nl * 16 + lr) * 72 + smi * 16 + lq * 4]) = pw;
      }
#pragma unroll
    for (int nl = 0; nl < 2; ++nl) {
      float s2 = ts[nl] + __shfl_xor(ts[nl], 16);
      s2 += __shfl_xor(s2, 32);
      l_run[nl] = l_run[nl] * scale[nl] + s2;
    }
#pragma unroll
    for (int dmi = 0; dmi < 4; ++dmi)
#pragma unroll
      for (int nl = 0; nl < 2; ++nl) oacc[dmi][nl] = oacc[dmi][nl] * scale[nl];

    // wave-level fence: P writes visible to this wave's lanes (no block barrier)
    asm volatile("s_waitcnt lgkmcnt(0)" ::: "memory");
    __builtin_amdgcn_sched_barrier(0);

    // O^T += V^T * P^T
#pragma unroll
    for (int ks = 0; ks < 2; ++ks) {
      s16x8 pf[2];
#pragma unroll
      for (int nl = 0; nl < 2; ++nl)
        pf[nl] = *(const s16x8*)(&Pl[w][(nl * 16 + lr) * 72 + ks * 32 + lq * 8]);
#pragma unroll
      for (int dmi = 0; dmi < 4; ++dmi) {
        const int d = dmi * 16 + lr;
        const s16x8 vf =
            *(const s16x8*)(Vt + d * 64 + ((ks * 32 + lq * 8) ^ ((d & 7) << 3)));
#pragma unroll
        for (int nl = 0; nl < 2; ++nl)
          oacc[dmi][nl] = MFMA16(vf, pf[nl], oacc[dmi][nl]);
      }
    }
  }

  // epilogue: normalize, write O as row-major (8192 x 512), k-swizzled for gemm_outproj
#pragma unroll
  for (int nl = 0; nl < 2; ++nl) {
    const float inv = 1.0f / l_run[nl];
    const int l = q0 + w * 32 + nl * 16 + lr;
    const int rout = l * 8 + nn;
#pragma unroll
    for (int dmi = 0; dmi < 4; ++dmi)
#pragma unroll
      for (int r = 0; r < 4; ++r) {
        const int d = dmi * 16 + lq * 4 + r;
        const int kout = hh * 64 + d;
        Og[(size_t)rout * 512 + (kout ^ (((rout >> 1) & 3) << 3))] =
            f2bf(oacc[dmi][nl][r] * inv);
      }
  }
}

// ---------------------------------------------------------------------------
// Kernel 3: out_proj GEMM  out = O(8192x512) * Wo^T(512x512) + bias, fp32 out.
// ---------------------------------------------------------------------------
__global__ __launch_bounds__(256) void gemm_outproj(
    const u16* __restrict__ A, const u16* __restrict__ W,
    const float* __restrict__ bias, float* __restrict__ out) {
  __shared__ __attribute__((aligned(16))) u16 At[128 * 32];
  __shared__ __attribute__((aligned(16))) u16 Bt[128 * 32];
  const int tid = threadIdx.x;
  const int lane = tid & 63, w = tid >> 6;
  const int lr = lane & 15, lq = lane >> 4;
  const int wr = w >> 1, wc = w & 1;
  const int tm = blockIdx.x * 128, tn = blockIdx.y * 128;

  f32x4 acc[4][4] = {};

  for (int k0 = 0; k0 < 512; k0 += 32) {
    if (k0) __syncthreads();
#pragma unroll
    for (int j = 0; j < 2; ++j) {
      const int c = (w * 2 + j) * 64 + lane;
      const int row = c >> 2;
      const int col = (c & 3) * 8;
      gload_lds16(A + (size_t)(tm + row) * 512 + k0 + col, At + (w * 2 + j) * 512);
      gload_lds16(W + (size_t)(tn + row) * 512 + k0 + col, Bt + (w * 2 + j) * 512);
    }
    __syncthreads();
    s16x8 af[4], bf[4];
#pragma unroll
    for (int mi = 0; mi < 4; ++mi) {
      const int row = wr * 64 + mi * 16 + lr;
      const int col = (lq * 8) ^ ((((tm + row) >> 1) & 3) << 3);
      af[mi] = *(const s16x8*)(At + row * 32 + col);
    }
#pragma unroll
    for (int ni = 0; ni < 4; ++ni) {
      const int row = wc * 64 + ni * 16 + lr;
      const int col = (lq * 8) ^ ((((tn + row) >> 1) & 3) << 3);
      bf[ni] = *(const s16x8*)(Bt + row * 32 + col);
    }
#pragma unroll
    for (int mi = 0; mi < 4; ++mi)
#pragma unroll
      for (int ni = 0; ni < 4; ++ni)
        acc[mi][ni] = MFMA16(af[mi], bf[ni], acc[mi][ni]);
  }

#pragma unroll
  for (int ni = 0; ni < 4; ++ni) {
    const int gc = tn + wc * 64 + ni * 16 + lr;
    const float bv = bias[gc];
#pragma unroll
    for (int mi = 0; mi < 4; ++mi)
#pragma unroll
      for (int r = 0; r < 4; ++r) {
        const int gr = tm + wr * 64 + mi * 16 + lq * 4 + r;
        out[(size_t)gr * 512 + gc] = acc[mi][ni][r] + bv;
      }
  }
}

// ---------------------------------------------------------------------------
extern "C" void kernel_launch(void* const* d_in, const int* in_sizes, int n_in,
                              void* d_out, int out_size, void* d_ws, size_t ws_size,
                              hipStream_t stream) {
  const float* query = (const float*)d_in[0];   // (1024, 8, 512)
  const float* w_in = (const float*)d_in[1];    // (2560, 512)
  const float* b_in = (const float*)d_in[2];    // (2560,)
  const float* w_out = (const float*)d_in[3];   // (512, 512)
  const float* b_out = (const float*)d_in[4];   // (512,)
  const float* mask = (const float*)d_in[5];    // (1024, 1024)

  char* ws = (char*)d_ws;
  u16* Xbf = (u16*)(ws + 0);          // 8192x512   bf16 swz
  u16* Wbf = (u16*)(ws + 8388608);    // 2560x512   bf16 swz
  u16* Wobf = (u16*)(ws + 11010048);  // 512x512    bf16 swz
  u16* Qg = (u16*)(ws + 11534336);    // [64][1024][64]
  u16* Kg = (u16*)(ws + 19922944);    // [64][1024][64] d-swz
  u16* Vtg = (u16*)(ws + 28311552);   // [64][64][1024] s-swz (transposed)
  u16* Qsg = (u16*)(ws + 36700160);
  u16* Ksg = (u16*)(ws + 45088768);
  u16* Og = (u16*)(ws + 53477376);    // 8192x512 bf16 swz

  hipLaunchKernelGGL(cvt_swz, dim3(4096), dim3(256), 0, stream, query, Xbf, 1048576);
  hipLaunchKernelGGL(cvt_swz, dim3(1280), dim3(256), 0, stream, w_in, Wbf, 327680);
  hipLaunchKernelGGL(cvt_swz, dim3(256), dim3(256), 0, stream, w_out, Wobf, 65536);
  hipLaunchKernelGGL(gemm_inproj, dim3(64, 20), dim3(256), 0, stream,
                     Xbf, Wbf, b_in, Qg, Kg, Vtg, Qsg, Ksg);
  hipLaunchKernelGGL(attn_kernel, dim3(8, 64), dim3(256), 0, stream,
                     Qg, Kg, Vtg, Qsg, Ksg, mask, Og);
  hipLaunchKernelGGL(gemm_outproj, dim3(64, 4), dim3(256), 0, stream,
                     Og, Wobf, b_out, (float*)d_out);
}

// Round 2
// 200.656 us; speedup vs baseline: 1.0866x; 1.0866x over previous
//
#include <hip/hip_runtime.h>

// Agent-aware MHA, MI355X (gfx950).
// L=1024, N=8, E=512, H=8, D=64. B-heads = 64. All GEMM/attn in bf16 MFMA.

typedef float f32x4 __attribute__((ext_vector_type(4)));
typedef short s16x8 __attribute__((ext_vector_type(8)));
typedef unsigned short u16;
typedef u16 u16x4 __attribute__((ext_vector_type(4)));
typedef unsigned int u32x2 __attribute__((ext_vector_type(2)));

#define MFMA16(a, b, c) __builtin_amdgcn_mfma_f32_16x16x32_bf16((a), (b), (c), 0, 0, 0)

__device__ __forceinline__ u16 f2bf(float f) {
  __bf16 h = (__bf16)f;  // RNE
  return __builtin_bit_cast(u16, h);
}
__device__ __forceinline__ unsigned int pack2(float a, float b) {
  return (unsigned int)f2bf(a) | ((unsigned int)f2bf(b) << 16);
}
__device__ __forceinline__ void gload_lds16(const u16* g, u16* l) {
  __builtin_amdgcn_global_load_lds(
      (const __attribute__((address_space(1))) void*)g,
      (__attribute__((address_space(3))) void*)l, 16, 0, 0);
}

// ---------------------------------------------------------------------------
// Kernel 0: fp32 -> bf16 convert with k-chunk XOR swizzle (rows of length 512).
// out[r][k ^ (((r>>1)&3)<<3)] = in[r][k]; swizzle stays within 32-elem k-chunks.
// ---------------------------------------------------------------------------
__global__ __launch_bounds__(256) void cvt_swz(const float* __restrict__ in,
                                               u16* __restrict__ out, int n4) {
  int i = blockIdx.x * 256 + threadIdx.x;
  if (i >= n4) return;
  f32x4 v = *(const f32x4*)(in + (size_t)i * 4);
  int e = i << 2;
  int r = e >> 9;
  int k = e & 511;
  int ks = k ^ (((r >> 1) & 3) << 3);
  u16x4 o;
  o[0] = f2bf(v[0]); o[1] = f2bf(v[1]); o[2] = f2bf(v[2]); o[3] = f2bf(v[3]);
  *(u16x4*)(out + ((size_t)r << 9) + ks) = o;
}

// ---------------------------------------------------------------------------
// Kernel 0b: pack binary fp32 mask into bits. Mp[l*16 + c] bit j = mask[l][c*64+j].
// ---------------------------------------------------------------------------
__global__ __launch_bounds__(256) void mask_pack(const float* __restrict__ m,
                                                 unsigned long long* __restrict__ out) {
  int i = blockIdx.x * 256 + threadIdx.x;
  unsigned long long b = __ballot(m[i] != 0.0f);
  if ((threadIdx.x & 63) == 0) out[i >> 6] = b;
}

// ---------------------------------------------------------------------------
// Kernel 1: in_proj GEMM  P = X(8192x512) * W^T(512x2560) + bias
// 128x128 tile, BK=64 (ks-split frag reads), 4 waves (2x2), 4x4 frags/wave.
// Epilogue scatters into per-head Q/K/Vt/Qs/Ks bf16 tensors:
//   Q,Qs : [bh][l][d]               (scaled by 0.125*log2e)
//   K,Ks : [bh][s][d ^ ((s&7)<<3)]  (d-swizzled for conflict-free ds_read)
//   Vt   : [bh][d][s ^ ((d&7)<<3)]  (transposed + s-swizzled)
// ---------------------------------------------------------------------------
__global__ __launch_bounds__(256) void gemm_inproj(
    const u16* __restrict__ X, const u16* __restrict__ W,
    const float* __restrict__ bias,
    u16* __restrict__ Qg, u16* __restrict__ Kg, u16* __restrict__ Vtg,
    u16* __restrict__ Qsg, u16* __restrict__ Ksg) {
  __shared__ __attribute__((aligned(16))) u16 At[128 * 64];
  __shared__ __attribute__((aligned(16))) u16 Bt[128 * 64];
  const int tid = threadIdx.x;
  const int lane = tid & 63, w = tid >> 6;
  const int lr = lane & 15, lq = lane >> 4;
  const int wr = w >> 1, wc = w & 1;
  const int tm = blockIdx.x * 128, tn = blockIdx.y * 128;

  f32x4 acc[4][4] = {};

  for (int k0 = 0; k0 < 512; k0 += 64) {
    if (k0) __syncthreads();
#pragma unroll
    for (int j = 0; j < 4; ++j) {
      const int c = (w * 4 + j) * 64 + lane;  // 16B chunk index, 1024 per tile
      const int row = c >> 3;
      const int col = (c & 7) * 8;
      gload_lds16(X + (size_t)(tm + row) * 512 + k0 + col, At + (w * 4 + j) * 512);
      gload_lds16(W + (size_t)(tn + row) * 512 + k0 + col, Bt + (w * 4 + j) * 512);
    }
    __syncthreads();
#pragma unroll
    for (int ks = 0; ks < 2; ++ks) {
      s16x8 af[4], bf[4];
#pragma unroll
      for (int mi = 0; mi < 4; ++mi) {
        const int row = wr * 64 + mi * 16 + lr;
        const int col = ks * 32 + ((lq * 8) ^ ((((tm + row) >> 1) & 3) << 3));
        af[mi] = *(const s16x8*)(At + row * 64 + col);
      }
#pragma unroll
      for (int ni = 0; ni < 4; ++ni) {
        const int row = wc * 64 + ni * 16 + lr;
        const int col = ks * 32 + ((lq * 8) ^ ((((tn + row) >> 1) & 3) << 3));
        bf[ni] = *(const s16x8*)(Bt + row * 64 + col);
      }
#pragma unroll
      for (int mi = 0; mi < 4; ++mi)
#pragma unroll
        for (int ni = 0; ni < 4; ++ni)
          acc[mi][ni] = MFMA16(af[mi], bf[ni], acc[mi][ni]);
    }
  }

  // Epilogue: 512/128=4 tiles per chunk -> chunk is block-uniform.
  const int chunk = tn >> 9;
  const float qscale = 0.125f * 1.4426950408889634f;  // scaling * log2(e)
#pragma unroll
  for (int ni = 0; ni < 4; ++ni) {
    const int gc = tn + wc * 64 + ni * 16 + lr;
    const float bv = bias[gc];
    const int e = gc & 511;
    const int hh = e >> 6, dd = e & 63;
#pragma unroll
    for (int mi = 0; mi < 4; ++mi) {
#pragma unroll
      for (int r = 0; r < 4; ++r) {
        const int gr = tm + wr * 64 + mi * 16 + lq * 4 + r;  // C/D: row=(lane>>4)*4+reg
        const int l = gr >> 3, nn = gr & 7;
        const size_t base = (size_t)(nn * 8 + hh) << 16;  // bh * L * D
        float v = acc[mi][ni][r] + bv;
        if (chunk == 0) {
          Qg[base + l * 64 + dd] = f2bf(v * qscale);
        } else if (chunk == 3) {
          Qsg[base + l * 64 + dd] = f2bf(v * qscale);
        } else if (chunk == 1) {
          Kg[base + l * 64 + (dd ^ ((l & 7) << 3))] = f2bf(v);
        } else if (chunk == 4) {
          Ksg[base + l * 64 + (dd ^ ((l & 7) << 3))] = f2bf(v);
        } else {  // chunk == 2: V stored transposed [bh][d][s], s-swizzled
          Vtg[base + (size_t)dd * 1024 + (l ^ ((dd & 7) << 3))] = f2bf(v);
        }
      }
    }
  }
}

// ---------------------------------------------------------------------------
// Kernel 2: fused dual attention. Block = (64 q-rows, one bh), 4 waves, each
// wave owns 16 q-rows. Grid (16,64)=1024 blocks -> 4 blocks/CU, 16 waves/CU.
// Swapped QK^T (S^T = mfma(K,Q)); binary mask via packed bits (cndmask);
// online softmax in exp2 domain with defer-max (THR=8); PV as O^T = V^T P^T.
// ---------------------------------------------------------------------------
__global__ __launch_bounds__(256, 4) void attn_kernel(
    const u16* __restrict__ Qg, const u16* __restrict__ Kg,
    const u16* __restrict__ Vtg, const u16* __restrict__ Qsg,
    const u16* __restrict__ Ksg, const unsigned long long* __restrict__ Mp,
    u16* __restrict__ Og) {
  __shared__ __attribute__((aligned(16))) u16 Kt[64 * 64];
  __shared__ __attribute__((aligned(16))) u16 Kst[64 * 64];
  __shared__ __attribute__((aligned(16))) u16 Vt[64 * 64];
  __shared__ __attribute__((aligned(16))) u16 Pl[4][16 * 72];  // wave-private

  const int tid = threadIdx.x;
  const int lane = tid & 63, w = tid >> 6;
  const int lr = lane & 15, lq = lane >> 4;
  const int bh = blockIdx.y;
  const int q0 = blockIdx.x * 64;
  const size_t bbase = (size_t)bh << 16;
  const int nn = bh >> 3, hh = bh & 7;
  const int l = q0 + w * 16 + lr;  // this lane's q-row

  // Q fragments (B-operand: n = l = lane&15, k = d contiguous). Held all loop.
  s16x8 qf[2], qsf[2];
#pragma unroll
  for (int ks = 0; ks < 2; ++ks) {
    qf[ks] = *(const s16x8*)(Qg + bbase + (size_t)l * 64 + ks * 32 + lq * 8);
    qsf[ks] = *(const s16x8*)(Qsg + bbase + (size_t)l * 64 + ks * 32 + lq * 8);
  }

  f32x4 oacc[4] = {};  // O^T fragments [dmi], col = l
  float m_run = -1e30f, l_run = 0.f;

  for (int t = 0; t < 16; ++t) {
    const int s0 = t * 64;
    if (t) __syncthreads();  // prior-iter LDS reads done before restage
#pragma unroll
    for (int j = 0; j < 2; ++j) {
      const int cb = (w * 2 + j) * 64;
      const int c = cb + lane;
      const int row = c >> 3, col = (c & 7) * 8;
      gload_lds16(Kg + bbase + (size_t)(s0 + row) * 64 + col, Kt + cb * 8);
      gload_lds16(Ksg + bbase + (size_t)(s0 + row) * 64 + col, Kst + cb * 8);
      gload_lds16(Vtg + bbase + (size_t)row * 1024 + s0 + col, Vt + cb * 8);
    }
    const unsigned long long mw = Mp[(size_t)l * 16 + t];  // overlaps barrier wait
    __syncthreads();

    // S^T = K * Q^T (A = K rows=s, B = Q cols=l); dual (diff & same)
    f32x4 sd[4] = {}, ss[4] = {};
    __builtin_amdgcn_s_setprio(1);
#pragma unroll
    for (int smi = 0; smi < 4; ++smi) {
      const int srow = smi * 16 + lr;
      const int sw = (srow & 7) << 3;
#pragma unroll
      for (int ks = 0; ks < 2; ++ks) {
        const int off = srow * 64 + ((ks * 32 + lq * 8) ^ sw);
        const s16x8 kf = *(const s16x8*)(Kt + off);
        const s16x8 kfs = *(const s16x8*)(Kst + off);
        sd[smi] = MFMA16(kf, qf[ks], sd[smi]);
        ss[smi] = MFMA16(kfs, qsf[ks], ss[smi]);
      }
    }
    __builtin_amdgcn_s_setprio(0);

    // select by mask bit (mask is binary): logit = bit ? ss : sd
    float mt = -1e30f;
#pragma unroll
    for (int smi = 0; smi < 4; ++smi) {
      const unsigned nib = (unsigned)(mw >> (smi * 16 + lq * 4));
#pragma unroll
      for (int r = 0; r < 4; ++r) {
        const float v = (nib & (1u << r)) ? ss[smi][r] : sd[smi][r];
        sd[smi][r] = v;
        mt = fmaxf(mt, v);
      }
    }
    mt = fmaxf(mt, __shfl_xor(mt, 16));
    mt = fmaxf(mt, __shfl_xor(mt, 32));

    // defer-max: skip rescale while max growth <= 8 (exp2 domain)
    if (!__all(mt <= m_run + 8.0f)) {
      const float mnew = fmaxf(m_run, mt);
      const float sc = exp2f(m_run - mnew);
      m_run = mnew;
      l_run *= sc;
#pragma unroll
      for (int dmi = 0; dmi < 4; ++dmi) oacc[dmi] *= sc;
    }

    float ts = 0.f;
#pragma unroll
    for (int smi = 0; smi < 4; ++smi)
#pragma unroll
      for (int r = 0; r < 4; ++r) {
        const float p = exp2f(sd[smi][r] - m_run);
        sd[smi][r] = p;
        ts += p;
      }
    // P -> wave-private LDS in [l][s] layout (B-operand for PV)
#pragma unroll
    for (int smi = 0; smi < 4; ++smi) {
      u32x2 pw;
      pw[0] = pack2(sd[smi][0], sd[smi][1]);
      pw[1] = pack2(sd[smi][2], sd[smi][3]);
      *(u32x2*)(&Pl[w][lr * 72 + smi * 16 + lq * 4]) = pw;
    }
    ts += __shfl_xor(ts, 16);
    ts += __shfl_xor(ts, 32);
    l_run += ts;

    // wave-level fence: P writes visible to this wave's lanes (no block barrier)
    asm volatile("s_waitcnt lgkmcnt(0)" ::: "memory");
    __builtin_amdgcn_sched_barrier(0);

    // O^T += V^T * P^T
    __builtin_amdgcn_s_setprio(1);
#pragma unroll
    for (int ks = 0; ks < 2; ++ks) {
      const s16x8 pf = *(const s16x8*)(&Pl[w][lr * 72 + ks * 32 + lq * 8]);
#pragma unroll
      for (int dmi = 0; dmi < 4; ++dmi) {
        const int d = dmi * 16 + lr;
        const s16x8 vf =
            *(const s16x8*)(Vt + d * 64 + ((ks * 32 + lq * 8) ^ ((d & 7) << 3)));
        oacc[dmi] = MFMA16(vf, pf, oacc[dmi]);
      }
    }
    __builtin_amdgcn_s_setprio(0);
  }

  // epilogue: normalize, write O row-major (8192x512), k-swizzled for out_proj
  const float inv = 1.0f / l_run;
  const int rout = l * 8 + nn;
  const int swzr = ((rout >> 1) & 3) << 3;
#pragma unroll
  for (int dmi = 0; dmi < 4; ++dmi) {
    u16x4 o;
#pragma unroll
    for (int r = 0; r < 4; ++r) o[r] = f2bf(oacc[dmi][r] * inv);
    const int kout = (hh * 64 + dmi * 16 + lq * 4) ^ swzr;  // low 3 bits untouched
    *(u16x4*)(Og + (size_t)rout * 512 + kout) = o;
  }
}

// ---------------------------------------------------------------------------
// Kernel 3: out_proj GEMM  out = O(8192x512) * Wo^T(512x512) + bias, fp32 out.
// 128x64 tile (grid 64x8 = 512 blocks), BK=64 ks-split. Waves 2x2: 64x32 each.
// ---------------------------------------------------------------------------
__global__ __launch_bounds__(256) void gemm_outproj(
    const u16* __restrict__ A, const u16* __restrict__ W,
    const float* __restrict__ bias, float* __restrict__ out) {
  __shared__ __attribute__((aligned(16))) u16 At[128 * 64];
  __shared__ __attribute__((aligned(16))) u16 Bt[64 * 64];
  const int tid = threadIdx.x;
  const int lane = tid & 63, w = tid >> 6;
  const int lr = lane & 15, lq = lane >> 4;
  const int wr = w >> 1, wc = w & 1;
  const int tm = blockIdx.x * 128, tn = blockIdx.y * 64;

  f32x4 acc[4][2] = {};

  for (int k0 = 0; k0 < 512; k0 += 64) {
    if (k0) __syncthreads();
#pragma unroll
    for (int j = 0; j < 4; ++j) {
      const int c = (w * 4 + j) * 64 + lane;
      const int row = c >> 3;
      const int col = (c & 7) * 8;
      gload_lds16(A + (size_t)(tm + row) * 512 + k0 + col, At + (w * 4 + j) * 512);
    }
#pragma unroll
    for (int j = 0; j < 2; ++j) {
      const int c = (w * 2 + j) * 64 + lane;
      const int row = c >> 3;
      const int col = (c & 7) * 8;
      gload_lds16(W + (size_t)(tn + row) * 512 + k0 + col, Bt + (w * 2 + j) * 512);
    }
    __syncthreads();
#pragma unroll
    for (int ks = 0; ks < 2; ++ks) {
      s16x8 af[4], bf[2];
#pragma unroll
      for (int mi = 0; mi < 4; ++mi) {
        const int row = wr * 64 + mi * 16 + lr;
        const int col = ks * 32 + ((lq * 8) ^ ((((tm + row) >> 1) & 3) << 3));
        af[mi] = *(const s16x8*)(At + row * 64 + col);
      }
#pragma unroll
      for (int ni = 0; ni < 2; ++ni) {
        const int row = wc * 32 + ni * 16 + lr;
        const int col = ks * 32 + ((lq * 8) ^ ((((tn + row) >> 1) & 3) << 3));
        bf[ni] = *(const s16x8*)(Bt + row * 64 + col);
      }
#pragma unroll
      for (int mi = 0; mi < 4; ++mi)
#pragma unroll
        for (int ni = 0; ni < 2; ++ni)
          acc[mi][ni] = MFMA16(af[mi], bf[ni], acc[mi][ni]);
    }
  }

#pragma unroll
  for (int ni = 0; ni < 2; ++ni) {
    const int gc = tn + wc * 32 + ni * 16 + lr;
    const float bv = bias[gc];
#pragma unroll
    for (int mi = 0; mi < 4; ++mi)
#pragma unroll
      for (int r = 0; r < 4; ++r) {
        const int gr = tm + wr * 64 + mi * 16 + lq * 4 + r;
        out[(size_t)gr * 512 + gc] = acc[mi][ni][r] + bv;
      }
  }
}

// ---------------------------------------------------------------------------
extern "C" void kernel_launch(void* const* d_in, const int* in_sizes, int n_in,
                              void* d_out, int out_size, void* d_ws, size_t ws_size,
                              hipStream_t stream) {
  const float* query = (const float*)d_in[0];   // (1024, 8, 512)
  const float* w_in = (const float*)d_in[1];    // (2560, 512)
  const float* b_in = (const float*)d_in[2];    // (2560,)
  const float* w_out = (const float*)d_in[3];   // (512, 512)
  const float* b_out = (const float*)d_in[4];   // (512,)
  const float* mask = (const float*)d_in[5];    // (1024, 1024)

  char* ws = (char*)d_ws;
  u16* Xbf = (u16*)(ws + 0);          // 8192x512 bf16 swz (dead after in_proj)
  u16* Wbf = (u16*)(ws + 8388608);    // 2560x512 bf16 swz
  u16* Wobf = (u16*)(ws + 11010048);  // 512x512  bf16 swz
  u16* Qg = (u16*)(ws + 11534336);    // [64][1024][64]
  u16* Kg = (u16*)(ws + 19922944);    // [64][1024][64] d-swz
  u16* Vtg = (u16*)(ws + 28311552);   // [64][64][1024] s-swz (transposed)
  u16* Qsg = (u16*)(ws + 36700160);
  u16* Ksg = (u16*)(ws + 45088768);
  u16* Og = (u16*)(ws + 53477376);    // 8192x512 bf16 swz
  unsigned long long* Mp = (unsigned long long*)(ws + 0);  // 128KB, reuses Xbf

  hipLaunchKernelGGL(cvt_swz, dim3(4096), dim3(256), 0, stream, query, Xbf, 1048576);
  hipLaunchKernelGGL(cvt_swz, dim3(1280), dim3(256), 0, stream, w_in, Wbf, 327680);
  hipLaunchKernelGGL(cvt_swz, dim3(256), dim3(256), 0, stream, w_out, Wobf, 65536);
  hipLaunchKernelGGL(gemm_inproj, dim3(64, 20), dim3(256), 0, stream,
                     Xbf, Wbf, b_in, Qg, Kg, Vtg, Qsg, Ksg);
  hipLaunchKernelGGL(mask_pack, dim3(4096), dim3(256), 0, stream, mask, Mp);
  hipLaunchKernelGGL(attn_kernel, dim3(16, 64), dim3(256), 0, stream,
                     Qg, Kg, Vtg, Qsg, Ksg, Mp, Og);
  hipLaunchKernelGGL(gemm_outproj, dim3(64, 8), dim3(256), 0, stream,
                     Og, Wobf, b_out, (float*)d_out);
}